// Round 28
// baseline (121.752 us; speedup 1.0000x reference)
//
#include <hip/hip_runtime.h>

// ---------------------------------------------------------------------------
// 2-layer TransformerConv factored through the 2-dim feature spaces.
// Round 28 (= round 27 + bugfix): round 27 failed because the accumulator
// clear `if (t < 3*R_DSTS)` covered only 256 of 384 entries at 256 threads
// -- ac[256..383] (the sum w*xs1 row) was garbage. Fixed with a strided
// clear. Otherwise identical: l1proj = 256 threads / 8-lane group per FOUR
// nodes (weight float4 reads reused 4x -> 28 LDS reads per node vs 56),
// phased body; scatter + l2out are the round-25 verified versions.
// Pipeline: memset(cnt) -> scatter1 -> l1proj -> l2out.
// ---------------------------------------------------------------------------

#define R_LOG2   7
#define R_DSTS   128            // dsts per bucket
#define BE       4096           // edges per partition block
#define MAXNB    1024           // supports N <= 131072
#define CAPB     2432           // slots per bucket (mean 2048, 8.5 sigma), %4==0
#define RSQRT2   0.70710678118654752f

// Single-pass locally-sorted scatter, 1024 threads (16 waves) per block.
// (Verified rounds 14-26.)
__global__ __launch_bounds__(1024) void scatter1_k(
        const int* __restrict__ src, const int* __restrict__ dst,
        int* __restrict__ cnt, int* __restrict__ recs, int NB, int E) {
    __shared__ int hist[MAXNB];
    __shared__ int lofs[MAXNB];
    __shared__ int gbase[MAXNB];
    __shared__ int stage[BE];
    __shared__ unsigned short sbkt[BE];
    __shared__ int wsum[16];
    int t = threadIdx.x;
    if (t < NB) hist[t] = 0;
    __syncthreads();

    int base = blockIdx.x * BE;
    int nloc = E - base; if (nloc > BE) nloc = BE;
    int nv = nloc >> 2;
    const int4* d4 = (const int4*)(dst + base);
    const int4* s4 = (const int4*)(src + base);

    // pass 1: local histogram (4 edges/thread via int4)
    for (int i = t; i < nv; i += 1024) {
        int4 v = d4[i];
        atomicAdd(&hist[v.x >> R_LOG2], 1);
        atomicAdd(&hist[v.y >> R_LOG2], 1);
        atomicAdd(&hist[v.z >> R_LOG2], 1);
        atomicAdd(&hist[v.w >> R_LOG2], 1);
    }
    for (int i = (nv << 2) + t; i < nloc; i += 1024)
        atomicAdd(&hist[dst[base + i] >> R_LOG2], 1);
    __syncthreads();

    // in-block exclusive scan hist -> lofs (1 entry/thread, NB<=1024)
    {
        int v = (t < NB) ? hist[t] : 0;
        int lane = t & 63, w = t >> 6;   // 16 waves
        int incl = v;
#pragma unroll
        for (int o = 1; o < 64; o <<= 1) {
            int u = __shfl_up(incl, o);
            if (lane >= o) incl += u;
        }
        if (lane == 63) wsum[w] = incl;
        __syncthreads();
        int ex = incl - v;
        for (int j = 0; j < w; ++j) ex += wsum[j];
        if (t < NB) lofs[t] = ex;
    }
    __syncthreads();

    // reserve a contiguous segment in each touched bucket, reset hist
    if (t < NB) {
        int h = hist[t];
        int start = h ? atomicAdd(&cnt[t], h) : 0;
        gbase[t] = t * CAPB + start - lofs[t];
        hist[t] = 0;
    }
    __syncthreads();

    // pass 2: rank & stage in bucket-sorted order
    for (int i = t; i < nv; i += 1024) {
        int4 dv = d4[i];
        int4 sv = s4[i];
        int d, b, r, p;
        d = dv.x; b = d >> R_LOG2; r = atomicAdd(&hist[b], 1); p = lofs[b] + r;
        stage[p] = sv.x | ((d & (R_DSTS - 1)) << 17); sbkt[p] = (unsigned short)b;
        d = dv.y; b = d >> R_LOG2; r = atomicAdd(&hist[b], 1); p = lofs[b] + r;
        stage[p] = sv.y | ((d & (R_DSTS - 1)) << 17); sbkt[p] = (unsigned short)b;
        d = dv.z; b = d >> R_LOG2; r = atomicAdd(&hist[b], 1); p = lofs[b] + r;
        stage[p] = sv.z | ((d & (R_DSTS - 1)) << 17); sbkt[p] = (unsigned short)b;
        d = dv.w; b = d >> R_LOG2; r = atomicAdd(&hist[b], 1); p = lofs[b] + r;
        stage[p] = sv.w | ((d & (R_DSTS - 1)) << 17); sbkt[p] = (unsigned short)b;
    }
    for (int i = (nv << 2) + t; i < nloc; i += 1024) {
        int d = dst[base + i];
        int b = d >> R_LOG2;
        int r = atomicAdd(&hist[b], 1);
        int p = lofs[b] + r;
        stage[p] = src[base + i] | ((d & (R_DSTS - 1)) << 17);
        sbkt[p] = (unsigned short)b;
    }
    __syncthreads();

    // pass 3: ordered write (bound-checked)
    for (int i = t; i < nloc; i += 1024) {
        int bk = sbkt[i];
        int p = gbase[bk] + i;
        if (p < (bk + 1) * CAPB) recs[p] = stage[i];
    }
}

// Layer-1 bucket reduce FUSED with projection. One 128-dst bucket per
// block, 256 threads. Projection: 8-lane group per FOUR nodes (32 groups
// x 4 = 128) -- each weight float4 read feeds 4 nodes. Phased body.
__global__ __launch_bounds__(256) void l1proj_k(
        const float* __restrict__ x,
        const float* __restrict__ Wq1, const float* __restrict__ bq1,
        const float* __restrict__ Wk1, const float* __restrict__ bk1,
        const float* __restrict__ Wv1, const float* __restrict__ bv1,
        const float* __restrict__ Ws1, const float* __restrict__ bs1,
        const float* __restrict__ Wq2, const float* __restrict__ bq2,
        const float* __restrict__ Wk2, const float* __restrict__ bk2,
        const float* __restrict__ Wv2, const float* __restrict__ bv2,
        const float* __restrict__ Ws2, const float* __restrict__ bs2,
        const int* __restrict__ recs, const int* __restrict__ cnt,
        float* __restrict__ q2, float4* __restrict__ kv2,
        float* __restrict__ hs2, int N) {
    __shared__ float cpart[4][9];
    __shared__ float c9[9];
    __shared__ float p0[R_DSTS], p1[R_DSTS], pc[R_DSTS];
    __shared__ float ac[3 * R_DSTS];
    __shared__ float sW[14][256];
    int t = threadIdx.x;

    // inline coeff reduction (alpha = xd^T M xs + u.xd + w.xs + c)
    {
        float wq0 = Wq1[t], wq1 = Wq1[256 + t];
        float wk0 = Wk1[t], wk1 = Wk1[256 + t];
        float bq = bq1[t], bk = bk1[t];
        float vals[9] = { wq0 * wk0, wq0 * wk1, wq1 * wk0, wq1 * wk1,
                          wq0 * bk,  wq1 * bk,  bq * wk0,  bq * wk1,  bq * bk };
        int lane = t & 63, w = t >> 6;
#pragma unroll
        for (int i = 0; i < 9; ++i) {
            float v = vals[i];
#pragma unroll
            for (int o = 32; o > 0; o >>= 1) v += __shfl_xor(v, o);
            if (lane == 0) cpart[w][i] = v;
        }
    }
    // weight staging (each thread loads its column of all 14 rows)
    sW[0][t]  = Wv1[t];
    sW[1][t]  = Wv1[256 + t];
    sW[2][t]  = Ws1[t];
    sW[3][t]  = Ws1[256 + t];
    sW[4][t]  = bv1[t];
    sW[5][t]  = bs1[t];
    sW[6][t]  = Wq2[2 * t];
    sW[7][t]  = Wq2[2 * t + 1];
    sW[8][t]  = Wk2[2 * t];
    sW[9][t]  = Wk2[2 * t + 1];
    sW[10][t] = Wv2[2 * t];
    sW[11][t] = Wv2[2 * t + 1];
    sW[12][t] = Ws2[2 * t];
    sW[13][t] = Ws2[2 * t + 1];
    __syncthreads();
    if (t < 9) c9[t] = cpart[0][t] + cpart[1][t] + cpart[2][t] + cpart[3][t];
    __syncthreads();

    int b = blockIdx.x;
    int nbase = b << R_LOG2;
    int rem = N - nbase; if (rem > R_DSTS) rem = R_DSTS;

    // FIXED: strided clear covers all 3*R_DSTS = 384 entries at 256 threads
    for (int i = t; i < 3 * R_DSTS; i += 256) ac[i] = 0.f;
    if (t < rem) {
        float2 xd = ((const float2*)x)[nbase + t];
        p0[t] = c9[0] * xd.x + c9[2] * xd.y + c9[6];
        p1[t] = c9[1] * xd.x + c9[3] * xd.y + c9[7];
        pc[t] = c9[4] * xd.x + c9[5] * xd.y + c9[8];
    }
    __syncthreads();

    // ---- bucket edge reduce (int4 rec loads, 4 concurrent gathers) ----
    const float2* x2 = (const float2*)x;
    int cb = cnt[b]; if (cb > CAPB) cb = CAPB;
    const int* rb = recs + (size_t)b * CAPB;
    const int4* rb4 = (const int4*)rb;
    int nv4 = cb >> 2;
    for (int i = t; i < nv4; i += 256) {
        int4 r = rb4[i];
        int s0 = r.x & 0x1FFFF, d0 = (r.x >> 17) & (R_DSTS - 1);
        int s1 = r.y & 0x1FFFF, d1 = (r.y >> 17) & (R_DSTS - 1);
        int s2 = r.z & 0x1FFFF, d2 = (r.z >> 17) & (R_DSTS - 1);
        int s3 = r.w & 0x1FFFF, d3 = (r.w >> 17) & (R_DSTS - 1);
        float2 xa = x2[s0];
        float2 xb = x2[s1];
        float2 xc = x2[s2];
        float2 xd = x2[s3];
        float w0 = __expf((p0[d0] * xa.x + p1[d0] * xa.y + pc[d0]) * 0.0625f);
        float w1 = __expf((p0[d1] * xb.x + p1[d1] * xb.y + pc[d1]) * 0.0625f);
        float w2 = __expf((p0[d2] * xc.x + p1[d2] * xc.y + pc[d2]) * 0.0625f);
        float w3 = __expf((p0[d3] * xd.x + p1[d3] * xd.y + pc[d3]) * 0.0625f);
        atomicAdd(&ac[d0], w0); atomicAdd(&ac[R_DSTS + d0], w0 * xa.x); atomicAdd(&ac[2 * R_DSTS + d0], w0 * xa.y);
        atomicAdd(&ac[d1], w1); atomicAdd(&ac[R_DSTS + d1], w1 * xb.x); atomicAdd(&ac[2 * R_DSTS + d1], w1 * xb.y);
        atomicAdd(&ac[d2], w2); atomicAdd(&ac[R_DSTS + d2], w2 * xc.x); atomicAdd(&ac[2 * R_DSTS + d2], w2 * xc.y);
        atomicAdd(&ac[d3], w3); atomicAdd(&ac[R_DSTS + d3], w3 * xd.x); atomicAdd(&ac[2 * R_DSTS + d3], w3 * xd.y);
    }
    for (int i = (nv4 << 2) + t; i < cb; i += 256) {
        int rec = rb[i];
        int s = rec & 0x1FFFF;
        int dl = (rec >> 17) & (R_DSTS - 1);
        float2 xs = x2[s];
        float w = __expf((p0[dl] * xs.x + p1[dl] * xs.y + pc[dl]) * 0.0625f);
        atomicAdd(&ac[dl], w);
        atomicAdd(&ac[R_DSTS + dl], w * xs.x);
        atomicAdd(&ac[2 * R_DSTS + dl], w * xs.y);
    }
    __syncthreads();

    // ---- fused projection: 8-lane group per FOUR nodes (32x4 = 128) ----
    int g = t & 7;
    int grp = t >> 3;                       // 0..31
    int i0 = grp * 4;                       // local node index base

    float a0[4], a1[4], he[4], xdx[4], xdy[4];
#pragma unroll
    for (int k = 0; k < 4; ++k) {
        int idx = i0 + k;
        int n = nbase + idx;
        a0[k] = 0.f; a1[k] = 0.f; he[k] = 0.f; xdx[k] = 0.f; xdy[k] = 0.f;
        if (idx < rem) {
            float s = ac[idx];              // LDS broadcast (full sums)
            if (s > 0.f) {
                float inv = 1.0f / s;
                a0[k] = ac[R_DSTS + idx] * inv;
                a1[k] = ac[2 * R_DSTS + idx] * inv;
                he[k] = 1.f;
            }
            float2 xd = ((const float2*)x)[n];
            xdx[k] = xd.x; xdy[k] = xd.y;
        }
    }

    float acc[4][8];
#pragma unroll
    for (int k = 0; k < 4; ++k)
#pragma unroll
        for (int i = 0; i < 8; ++i) acc[k][i] = 0.f;

#pragma unroll 1
    for (int j = 0; j < 8; ++j) {
        int ci = g + 8 * j;  // float4 index; channels 4*ci..4*ci+3
        // phase 1: hidden activations for the 4 nodes (w0..w5 live)
        float4 hk[4];
        {
            float4 w0 = ((const float4*)sW[0])[ci];
            float4 w1 = ((const float4*)sW[1])[ci];
            float4 w2 = ((const float4*)sW[2])[ci];
            float4 w3 = ((const float4*)sW[3])[ci];
            float4 w4 = ((const float4*)sW[4])[ci];
            float4 w5 = ((const float4*)sW[5])[ci];
#pragma unroll
            for (int k = 0; k < 4; ++k) {
                hk[k].x = fmaxf(a0[k]*w0.x + a1[k]*w1.x + xdx[k]*w2.x + xdy[k]*w3.x + he[k]*w4.x + w5.x, 0.f);
                hk[k].y = fmaxf(a0[k]*w0.y + a1[k]*w1.y + xdx[k]*w2.y + xdy[k]*w3.y + he[k]*w4.y + w5.y, 0.f);
                hk[k].z = fmaxf(a0[k]*w0.z + a1[k]*w1.z + xdx[k]*w2.z + xdy[k]*w3.z + he[k]*w4.z + w5.z, 0.f);
                hk[k].w = fmaxf(a0[k]*w0.w + a1[k]*w1.w + xdx[k]*w2.w + xdy[k]*w3.w + he[k]*w4.w + w5.w, 0.f);
            }
        }
        // phase 2: project, one output weight vector at a time
#pragma unroll
        for (int i = 0; i < 8; ++i) {
            float4 u = ((const float4*)sW[6 + i])[ci];
#pragma unroll
            for (int k = 0; k < 4; ++k)
                acc[k][i] += hk[k].x*u.x + hk[k].y*u.y + hk[k].z*u.z + hk[k].w*u.w;
        }
    }
#pragma unroll
    for (int k = 0; k < 4; ++k)
#pragma unroll
        for (int i = 0; i < 8; ++i) {
#pragma unroll
            for (int m = 1; m < 8; m <<= 1)
                acc[k][i] += __shfl_xor(acc[k][i], m);
        }
    if (g < 4) {
        int idx = i0 + g;
        int n = nbase + idx;
        if (idx < rem) {
            ((float2*)q2)[n]  = make_float2(acc[g][0] + bq2[0], acc[g][1] + bq2[1]);
            kv2[n] = make_float4(acc[g][2] + bk2[0], acc[g][3] + bk2[1],
                                 acc[g][4] + bv2[0], acc[g][5] + bv2[1]);
            ((float2*)hs2)[n] = make_float2(acc[g][6] + bs2[0], acc[g][7] + bs2[1]);
        }
    }
}

// Layer-2: one 128-dst bucket per block, 512 threads. (Verified round 25.)
__global__ __launch_bounds__(512) void l2out_k(
        const float* __restrict__ q2, const float4* __restrict__ kv2,
        const float* __restrict__ hs2,
        const int* __restrict__ recs, const int* __restrict__ cnt,
        float* __restrict__ out, int N) {
    __shared__ float qx[R_DSTS], qy[R_DSTS];
    __shared__ float ac[3 * R_DSTS];
    int t = threadIdx.x;
    int b = blockIdx.x;
    int nbase = b << R_LOG2;
    int rem = N - nbase; if (rem > R_DSTS) rem = R_DSTS;

    if (t < 3 * R_DSTS) ac[t] = 0.f;
    if (t < rem) {
        float2 q = ((const float2*)q2)[nbase + t];
        qx[t] = q.x * RSQRT2;
        qy[t] = q.y * RSQRT2;
    }
    __syncthreads();

    int cb = cnt[b]; if (cb > CAPB) cb = CAPB;
    const int* rb = recs + (size_t)b * CAPB;
    const int4* rb4 = (const int4*)rb;
    int nv4 = cb >> 2;
    for (int i = t; i < nv4; i += 512) {
        int4 r = rb4[i];
        int s0 = r.x & 0x1FFFF, d0 = (r.x >> 17) & (R_DSTS - 1);
        int s1 = r.y & 0x1FFFF, d1 = (r.y >> 17) & (R_DSTS - 1);
        int s2 = r.z & 0x1FFFF, d2 = (r.z >> 17) & (R_DSTS - 1);
        int s3 = r.w & 0x1FFFF, d3 = (r.w >> 17) & (R_DSTS - 1);
        float4 ka = kv2[s0];
        float4 kb = kv2[s1];
        float4 kc = kv2[s2];
        float4 kd = kv2[s3];
        float w0 = __expf(qx[d0] * ka.x + qy[d0] * ka.y);
        float w1 = __expf(qx[d1] * kb.x + qy[d1] * kb.y);
        float w2 = __expf(qx[d2] * kc.x + qy[d2] * kc.y);
        float w3 = __expf(qx[d3] * kd.x + qy[d3] * kd.y);
        atomicAdd(&ac[d0], w0); atomicAdd(&ac[R_DSTS + d0], w0 * ka.z); atomicAdd(&ac[2 * R_DSTS + d0], w0 * ka.w);
        atomicAdd(&ac[d1], w1); atomicAdd(&ac[R_DSTS + d1], w1 * kb.z); atomicAdd(&ac[2 * R_DSTS + d1], w1 * kb.w);
        atomicAdd(&ac[d2], w2); atomicAdd(&ac[R_DSTS + d2], w2 * kc.z); atomicAdd(&ac[2 * R_DSTS + d2], w2 * kc.w);
        atomicAdd(&ac[d3], w3); atomicAdd(&ac[R_DSTS + d3], w3 * kd.z); atomicAdd(&ac[2 * R_DSTS + d3], w3 * kd.w);
    }
    for (int i = (nv4 << 2) + t; i < cb; i += 512) {
        int rec = rb[i];
        int s = rec & 0x1FFFF;
        int dl = (rec >> 17) & (R_DSTS - 1);
        float4 kv = kv2[s];
        float w = __expf(qx[dl] * kv.x + qy[dl] * kv.y);
        atomicAdd(&ac[dl], w);
        atomicAdd(&ac[R_DSTS + dl], w * kv.z);
        atomicAdd(&ac[2 * R_DSTS + dl], w * kv.w);
    }
    __syncthreads();

    if (t < rem) {
        int n = nbase + t;
        float s = ac[t];
        float g0 = 0.f, g1 = 0.f;
        if (s > 0.f) {
            float inv = 1.0f / s;
            g0 = ac[R_DSTS + t] * inv; g1 = ac[2 * R_DSTS + t] * inv;
        }
        float2 hs = ((const float2*)hs2)[n];
        float o0 = g0 + hs.x;
        float o1 = g1 + hs.y;
        float mx = fmaxf(o0, o1), mn = fminf(o0, o1);
        float lse = mx + log1pf(__expf(mn - mx));
        ((float2*)out)[n] = make_float2(o0 - lse, o1 - lse);
    }
}

extern "C" void kernel_launch(void* const* d_in, const int* in_sizes, int n_in,
                              void* d_out, int out_size, void* d_ws, size_t ws_size,
                              hipStream_t stream) {
    const float* x   = (const float*)d_in[0];
    const int*   ei  = (const int*)d_in[1];
    const float* Wq1 = (const float*)d_in[2];
    const float* bq1 = (const float*)d_in[3];
    const float* Wk1 = (const float*)d_in[4];
    const float* bk1 = (const float*)d_in[5];
    const float* Wv1 = (const float*)d_in[6];
    const float* bv1 = (const float*)d_in[7];
    const float* Ws1 = (const float*)d_in[8];
    const float* bs1 = (const float*)d_in[9];
    const float* Wq2 = (const float*)d_in[10];
    const float* bq2 = (const float*)d_in[11];
    const float* Wk2 = (const float*)d_in[12];
    const float* bk2 = (const float*)d_in[13];
    const float* Wv2 = (const float*)d_in[14];
    const float* bv2 = (const float*)d_in[15];
    const float* Ws2 = (const float*)d_in[16];
    const float* bs2 = (const float*)d_in[17];

    const int N = in_sizes[0] / 2;
    const int E = in_sizes[1] / 2;
    const int* src = ei;
    const int* dst = ei + E;

    const int NB   = (N + R_DSTS - 1) >> R_LOG2;     // 782
    const int NBlk = (E + BE - 1) / BE;              // 391

    // workspace layout (4-byte units); recs at a 16B-aligned offset
    float* ws = (float*)d_ws;
    size_t off = 0;
    int*   cnt  = (int*)(ws + off);      off += MAXNB;             // padded
    int*   recs = (int*)(ws + off);      off += (size_t)NB * CAPB; // %4==0
    off = (off + 3) & ~(size_t)3;        // 16B align
    float4* kv2 = (float4*)(ws + off);   off += 4 * (size_t)N;
    float* q2   = ws + off;              off += 2 * (size_t)N;
    float* hs2  = ws + off;              off += 2 * (size_t)N;

    hipMemsetAsync(cnt, 0, NB * sizeof(int), stream);
    scatter1_k<<<NBlk, 1024, 0, stream>>>(src, dst, cnt, recs, NB, E);
    l1proj_k<<<NB, 256, 0, stream>>>(x, Wq1, bq1, Wk1, bk1,
                                     Wv1, bv1, Ws1, bs1,
                                     Wq2, bq2, Wk2, bk2, Wv2, bv2, Ws2, bs2,
                                     recs, cnt, q2, kv2, hs2, N);
    l2out_k<<<NB, 512, 0, stream>>>(q2, kv2, hs2, recs, cnt, (float*)d_out, N);
}

// Round 29
// 119.534 us; speedup vs baseline: 1.0186x; 1.0186x over previous
//
#include <hip/hip_runtime.h>

// ---------------------------------------------------------------------------
// 2-layer TransformerConv factored through the 2-dim feature spaces.
// Round 29 (= round 26 verbatim, the measured optimum at 119.9us):
// consolidation at the practical floor. Ledger: 12 structural variants span
// 119.9-127.8us with all HW counters <30% busy -- the cost is distributed
// gather latency + LDS-atomic serialization across 3 dependent stages, not
// any single counter-visible bottleneck.
// Pipeline: memset(cnt) -> scatter1 -> l1proj -> l2out (4 nodes).
// ---------------------------------------------------------------------------

#define R_LOG2   6
#define R_DSTS   64             // dsts per bucket
#define BE       4096           // edges per partition block
#define MAXNB    2048           // supports N <= 131072
#define CAPB     1216           // slots per bucket (mean 1024, ~6 sigma), %4==0
#define RSQRT2   0.70710678118654752f

// Single-pass locally-sorted scatter, 1024 threads (16 waves) per block.
// LDS histogram (2048 bins) -> in-block scan (2 entries/thread) -> global
// segment reservation -> rank & stage in bucket order -> ordered writes.
__global__ __launch_bounds__(1024) void scatter1_k(
        const int* __restrict__ src, const int* __restrict__ dst,
        int* __restrict__ cnt, int* __restrict__ recs, int NB, int E) {
    __shared__ int hist[MAXNB];
    __shared__ int lofs[MAXNB];
    __shared__ int gbase[MAXNB];
    __shared__ int stage[BE];
    __shared__ unsigned short sbkt[BE];
    __shared__ int wsum[16];
    int t = threadIdx.x;
    for (int i = t; i < NB; i += 1024) hist[i] = 0;
    __syncthreads();

    int base = blockIdx.x * BE;
    int nloc = E - base; if (nloc > BE) nloc = BE;
    int nv = nloc >> 2;
    const int4* d4 = (const int4*)(dst + base);
    const int4* s4 = (const int4*)(src + base);

    // pass 1: local histogram (4 edges/thread via int4)
    for (int i = t; i < nv; i += 1024) {
        int4 v = d4[i];
        atomicAdd(&hist[v.x >> R_LOG2], 1);
        atomicAdd(&hist[v.y >> R_LOG2], 1);
        atomicAdd(&hist[v.z >> R_LOG2], 1);
        atomicAdd(&hist[v.w >> R_LOG2], 1);
    }
    for (int i = (nv << 2) + t; i < nloc; i += 1024)
        atomicAdd(&hist[dst[base + i] >> R_LOG2], 1);
    __syncthreads();

    // in-block exclusive scan hist -> lofs (2 entries/thread, NB<=2048)
    {
        int i0 = 2 * t, i1 = 2 * t + 1;
        int a = (i0 < NB) ? hist[i0] : 0;
        int b = (i1 < NB) ? hist[i1] : 0;
        int s = a + b;
        int lane = t & 63, w = t >> 6;   // 16 waves
        int incl = s;
#pragma unroll
        for (int o = 1; o < 64; o <<= 1) {
            int u = __shfl_up(incl, o);
            if (lane >= o) incl += u;
        }
        if (lane == 63) wsum[w] = incl;
        __syncthreads();
        int ex = incl - s;
        for (int j = 0; j < w; ++j) ex += wsum[j];
        if (i0 < NB) lofs[i0] = ex;
        if (i1 < NB) lofs[i1] = ex + a;
    }
    __syncthreads();

    // reserve a contiguous segment in each touched bucket, reset hist
    for (int b = t; b < NB; b += 1024) {
        int h = hist[b];
        int start = h ? atomicAdd(&cnt[b], h) : 0;
        gbase[b] = b * CAPB + start - lofs[b];
        hist[b] = 0;
    }
    __syncthreads();

    // pass 2: rank & stage in bucket-sorted order
    for (int i = t; i < nv; i += 1024) {
        int4 dv = d4[i];
        int4 sv = s4[i];
        int d, b, r, p;
        d = dv.x; b = d >> R_LOG2; r = atomicAdd(&hist[b], 1); p = lofs[b] + r;
        stage[p] = sv.x | ((d & (R_DSTS - 1)) << 17); sbkt[p] = (unsigned short)b;
        d = dv.y; b = d >> R_LOG2; r = atomicAdd(&hist[b], 1); p = lofs[b] + r;
        stage[p] = sv.y | ((d & (R_DSTS - 1)) << 17); sbkt[p] = (unsigned short)b;
        d = dv.z; b = d >> R_LOG2; r = atomicAdd(&hist[b], 1); p = lofs[b] + r;
        stage[p] = sv.z | ((d & (R_DSTS - 1)) << 17); sbkt[p] = (unsigned short)b;
        d = dv.w; b = d >> R_LOG2; r = atomicAdd(&hist[b], 1); p = lofs[b] + r;
        stage[p] = sv.w | ((d & (R_DSTS - 1)) << 17); sbkt[p] = (unsigned short)b;
    }
    for (int i = (nv << 2) + t; i < nloc; i += 1024) {
        int d = dst[base + i];
        int b = d >> R_LOG2;
        int r = atomicAdd(&hist[b], 1);
        int p = lofs[b] + r;
        stage[p] = src[base + i] | ((d & (R_DSTS - 1)) << 17);
        sbkt[p] = (unsigned short)b;
    }
    __syncthreads();

    // pass 3: ordered write — consecutive i -> consecutive addresses per
    // segment; bound-checked against the bucket's fixed capacity.
    for (int i = t; i < nloc; i += 1024) {
        int bk = sbkt[i];
        int p = gbase[bk] + i;
        if (p < (bk + 1) * CAPB) recs[p] = stage[i];
    }
}

// Layer-1 bucket reduce FUSED with projection of the bucket's 64 nodes.
// One 64-dst bucket per block, 256 threads (1564 blocks, ~6/CU resident).
__global__ __launch_bounds__(256) void l1proj_k(
        const float* __restrict__ x,
        const float* __restrict__ Wq1, const float* __restrict__ bq1,
        const float* __restrict__ Wk1, const float* __restrict__ bk1,
        const float* __restrict__ Wv1, const float* __restrict__ bv1,
        const float* __restrict__ Ws1, const float* __restrict__ bs1,
        const float* __restrict__ Wq2, const float* __restrict__ bq2,
        const float* __restrict__ Wk2, const float* __restrict__ bk2,
        const float* __restrict__ Wv2, const float* __restrict__ bv2,
        const float* __restrict__ Ws2, const float* __restrict__ bs2,
        const int* __restrict__ recs, const int* __restrict__ cnt,
        float* __restrict__ q2, float4* __restrict__ kv2,
        float* __restrict__ hs2, int N) {
    __shared__ float cpart[4][9];
    __shared__ float c9[9];
    __shared__ float p0[R_DSTS], p1[R_DSTS], pc[R_DSTS];
    __shared__ float ac[3 * R_DSTS];
    __shared__ float sW[14][256];
    int t = threadIdx.x;

    // inline coeff reduction (alpha = xd^T M xs + u.xd + w.xs + c)
    {
        float wq0 = Wq1[t], wq1 = Wq1[256 + t];
        float wk0 = Wk1[t], wk1 = Wk1[256 + t];
        float bq = bq1[t], bk = bk1[t];
        float vals[9] = { wq0 * wk0, wq0 * wk1, wq1 * wk0, wq1 * wk1,
                          wq0 * bk,  wq1 * bk,  bq * wk0,  bq * wk1,  bq * bk };
        int lane = t & 63, w = t >> 6;
#pragma unroll
        for (int i = 0; i < 9; ++i) {
            float v = vals[i];
#pragma unroll
            for (int o = 32; o > 0; o >>= 1) v += __shfl_xor(v, o);
            if (lane == 0) cpart[w][i] = v;
        }
    }
    // weight staging (each thread loads its column of all 14 rows)
    sW[0][t]  = Wv1[t];
    sW[1][t]  = Wv1[256 + t];
    sW[2][t]  = Ws1[t];
    sW[3][t]  = Ws1[256 + t];
    sW[4][t]  = bv1[t];
    sW[5][t]  = bs1[t];
    sW[6][t]  = Wq2[2 * t];
    sW[7][t]  = Wq2[2 * t + 1];
    sW[8][t]  = Wk2[2 * t];
    sW[9][t]  = Wk2[2 * t + 1];
    sW[10][t] = Wv2[2 * t];
    sW[11][t] = Wv2[2 * t + 1];
    sW[12][t] = Ws2[2 * t];
    sW[13][t] = Ws2[2 * t + 1];
    __syncthreads();
    if (t < 9) c9[t] = cpart[0][t] + cpart[1][t] + cpart[2][t] + cpart[3][t];
    __syncthreads();

    int b = blockIdx.x;
    int nbase = b << R_LOG2;
    int rem = N - nbase; if (rem > R_DSTS) rem = R_DSTS;

    if (t < 3 * R_DSTS) ac[t] = 0.f;
    if (t < rem) {
        float2 xd = ((const float2*)x)[nbase + t];
        p0[t] = c9[0] * xd.x + c9[2] * xd.y + c9[6];
        p1[t] = c9[1] * xd.x + c9[3] * xd.y + c9[7];
        pc[t] = c9[4] * xd.x + c9[5] * xd.y + c9[8];
    }
    __syncthreads();

    // ---- bucket edge reduce (int4 rec loads, 4 concurrent gathers) ----
    const float2* x2 = (const float2*)x;
    int cb = cnt[b]; if (cb > CAPB) cb = CAPB;
    const int* rb = recs + (size_t)b * CAPB;
    const int4* rb4 = (const int4*)rb;
    int nv4 = cb >> 2;
    for (int i = t; i < nv4; i += 256) {
        int4 r = rb4[i];
        int s0 = r.x & 0x1FFFF, d0 = (r.x >> 17) & (R_DSTS - 1);
        int s1 = r.y & 0x1FFFF, d1 = (r.y >> 17) & (R_DSTS - 1);
        int s2 = r.z & 0x1FFFF, d2 = (r.z >> 17) & (R_DSTS - 1);
        int s3 = r.w & 0x1FFFF, d3 = (r.w >> 17) & (R_DSTS - 1);
        float2 xa = x2[s0];
        float2 xb = x2[s1];
        float2 xc = x2[s2];
        float2 xd = x2[s3];
        float w0 = __expf((p0[d0] * xa.x + p1[d0] * xa.y + pc[d0]) * 0.0625f);
        float w1 = __expf((p0[d1] * xb.x + p1[d1] * xb.y + pc[d1]) * 0.0625f);
        float w2 = __expf((p0[d2] * xc.x + p1[d2] * xc.y + pc[d2]) * 0.0625f);
        float w3 = __expf((p0[d3] * xd.x + p1[d3] * xd.y + pc[d3]) * 0.0625f);
        atomicAdd(&ac[d0], w0); atomicAdd(&ac[R_DSTS + d0], w0 * xa.x); atomicAdd(&ac[2 * R_DSTS + d0], w0 * xa.y);
        atomicAdd(&ac[d1], w1); atomicAdd(&ac[R_DSTS + d1], w1 * xb.x); atomicAdd(&ac[2 * R_DSTS + d1], w1 * xb.y);
        atomicAdd(&ac[d2], w2); atomicAdd(&ac[R_DSTS + d2], w2 * xc.x); atomicAdd(&ac[2 * R_DSTS + d2], w2 * xc.y);
        atomicAdd(&ac[d3], w3); atomicAdd(&ac[R_DSTS + d3], w3 * xd.x); atomicAdd(&ac[2 * R_DSTS + d3], w3 * xd.y);
    }
    for (int i = (nv4 << 2) + t; i < cb; i += 256) {
        int rec = rb[i];
        int s = rec & 0x1FFFF;
        int dl = (rec >> 17) & (R_DSTS - 1);
        float2 xs = x2[s];
        float w = __expf((p0[dl] * xs.x + p1[dl] * xs.y + pc[dl]) * 0.0625f);
        atomicAdd(&ac[dl], w);
        atomicAdd(&ac[R_DSTS + dl], w * xs.x);
        atomicAdd(&ac[2 * R_DSTS + dl], w * xs.y);
    }
    __syncthreads();

    // ---- fused projection of this bucket's 64 nodes ----
    // 8-lane group per TWO nodes: 256 threads = 32 groups x 2 = 64 nodes.
    int g = t & 7;
    int grp = t >> 3;                       // 0..31
    int i0 = grp * 2;                       // local node index base

    float a0[2], a1[2], he[2], xdx[2], xdy[2];
#pragma unroll
    for (int k = 0; k < 2; ++k) {
        int idx = i0 + k;
        int n = nbase + idx;
        a0[k] = 0.f; a1[k] = 0.f; he[k] = 0.f; xdx[k] = 0.f; xdy[k] = 0.f;
        if (idx < rem) {
            float s = ac[idx];              // LDS broadcast (full sums)
            if (s > 0.f) {
                float inv = 1.0f / s;
                a0[k] = ac[R_DSTS + idx] * inv;
                a1[k] = ac[2 * R_DSTS + idx] * inv;
                he[k] = 1.f;
            }
            float2 xd = ((const float2*)x)[n];
            xdx[k] = xd.x; xdy[k] = xd.y;
        }
    }

    float acc[2][8];
#pragma unroll
    for (int k = 0; k < 2; ++k)
#pragma unroll
        for (int i = 0; i < 8; ++i) acc[k][i] = 0.f;

#pragma unroll 1
    for (int j = 0; j < 8; ++j) {
        int ci = g + 8 * j;  // float4 index; channels 4*ci..4*ci+3
        float4 hk[2];
        {
            float4 w0 = ((const float4*)sW[0])[ci];
            float4 w1 = ((const float4*)sW[1])[ci];
            float4 w2 = ((const float4*)sW[2])[ci];
            float4 w3 = ((const float4*)sW[3])[ci];
            float4 w4 = ((const float4*)sW[4])[ci];
            float4 w5 = ((const float4*)sW[5])[ci];
#pragma unroll
            for (int k = 0; k < 2; ++k) {
                hk[k].x = fmaxf(a0[k]*w0.x + a1[k]*w1.x + xdx[k]*w2.x + xdy[k]*w3.x + he[k]*w4.x + w5.x, 0.f);
                hk[k].y = fmaxf(a0[k]*w0.y + a1[k]*w1.y + xdx[k]*w2.y + xdy[k]*w3.y + he[k]*w4.y + w5.y, 0.f);
                hk[k].z = fmaxf(a0[k]*w0.z + a1[k]*w1.z + xdx[k]*w2.z + xdy[k]*w3.z + he[k]*w4.z + w5.z, 0.f);
                hk[k].w = fmaxf(a0[k]*w0.w + a1[k]*w1.w + xdx[k]*w2.w + xdy[k]*w3.w + he[k]*w4.w + w5.w, 0.f);
            }
        }
#pragma unroll
        for (int i = 0; i < 8; ++i) {
            float4 u = ((const float4*)sW[6 + i])[ci];
#pragma unroll
            for (int k = 0; k < 2; ++k)
                acc[k][i] += hk[k].x*u.x + hk[k].y*u.y + hk[k].z*u.z + hk[k].w*u.w;
        }
    }
#pragma unroll
    for (int k = 0; k < 2; ++k)
#pragma unroll
        for (int i = 0; i < 8; ++i) {
#pragma unroll
            for (int m = 1; m < 8; m <<= 1)
                acc[k][i] += __shfl_xor(acc[k][i], m);
        }
    if (g < 2) {
        int idx = i0 + g;
        int n = nbase + idx;
        if (idx < rem) {
            ((float2*)q2)[n]  = make_float2(acc[g][0] + bq2[0], acc[g][1] + bq2[1]);
            kv2[n] = make_float4(acc[g][2] + bk2[0], acc[g][3] + bk2[1],
                                 acc[g][4] + bv2[0], acc[g][5] + bv2[1]);
            ((float2*)hs2)[n] = make_float2(acc[g][6] + bs2[0], acc[g][7] + bs2[1]);
        }
    }
}

// Layer-2: one 64-dst bucket per block, 256 threads. int4 rec loads ->
// 4 concurrent kv2 gathers; LDS-atomic accumulate, in-block finalize +
// skip + closed-form 2-class log_softmax.
__global__ __launch_bounds__(256) void l2out_k(
        const float* __restrict__ q2, const float4* __restrict__ kv2,
        const float* __restrict__ hs2,
        const int* __restrict__ recs, const int* __restrict__ cnt,
        float* __restrict__ out, int N) {
    __shared__ float qx[R_DSTS], qy[R_DSTS];
    __shared__ float ac[3 * R_DSTS];
    int t = threadIdx.x;
    int b = blockIdx.x;
    int nbase = b << R_LOG2;
    int rem = N - nbase; if (rem > R_DSTS) rem = R_DSTS;

    if (t < 3 * R_DSTS) ac[t] = 0.f;
    if (t < rem) {
        float2 q = ((const float2*)q2)[nbase + t];
        qx[t] = q.x * RSQRT2;
        qy[t] = q.y * RSQRT2;
    }
    __syncthreads();

    int cb = cnt[b]; if (cb > CAPB) cb = CAPB;
    const int* rb = recs + (size_t)b * CAPB;
    const int4* rb4 = (const int4*)rb;
    int nv4 = cb >> 2;
    for (int i = t; i < nv4; i += 256) {
        int4 r = rb4[i];
        int s0 = r.x & 0x1FFFF, d0 = (r.x >> 17) & (R_DSTS - 1);
        int s1 = r.y & 0x1FFFF, d1 = (r.y >> 17) & (R_DSTS - 1);
        int s2 = r.z & 0x1FFFF, d2 = (r.z >> 17) & (R_DSTS - 1);
        int s3 = r.w & 0x1FFFF, d3 = (r.w >> 17) & (R_DSTS - 1);
        float4 ka = kv2[s0];
        float4 kb = kv2[s1];
        float4 kc = kv2[s2];
        float4 kd = kv2[s3];
        float w0 = __expf(qx[d0] * ka.x + qy[d0] * ka.y);
        float w1 = __expf(qx[d1] * kb.x + qy[d1] * kb.y);
        float w2 = __expf(qx[d2] * kc.x + qy[d2] * kc.y);
        float w3 = __expf(qx[d3] * kd.x + qy[d3] * kd.y);
        atomicAdd(&ac[d0], w0); atomicAdd(&ac[R_DSTS + d0], w0 * ka.z); atomicAdd(&ac[2 * R_DSTS + d0], w0 * ka.w);
        atomicAdd(&ac[d1], w1); atomicAdd(&ac[R_DSTS + d1], w1 * kb.z); atomicAdd(&ac[2 * R_DSTS + d1], w1 * kb.w);
        atomicAdd(&ac[d2], w2); atomicAdd(&ac[R_DSTS + d2], w2 * kc.z); atomicAdd(&ac[2 * R_DSTS + d2], w2 * kc.w);
        atomicAdd(&ac[d3], w3); atomicAdd(&ac[R_DSTS + d3], w3 * kd.z); atomicAdd(&ac[2 * R_DSTS + d3], w3 * kd.w);
    }
    for (int i = (nv4 << 2) + t; i < cb; i += 256) {
        int rec = rb[i];
        int s = rec & 0x1FFFF;
        int dl = (rec >> 17) & (R_DSTS - 1);
        float4 kv = kv2[s];
        float w = __expf(qx[dl] * kv.x + qy[dl] * kv.y);
        atomicAdd(&ac[dl], w);
        atomicAdd(&ac[R_DSTS + dl], w * kv.z);
        atomicAdd(&ac[2 * R_DSTS + dl], w * kv.w);
    }
    __syncthreads();

    if (t < rem) {
        int n = nbase + t;
        float s = ac[t];
        float g0 = 0.f, g1 = 0.f;
        if (s > 0.f) {
            float inv = 1.0f / s;
            g0 = ac[R_DSTS + t] * inv; g1 = ac[2 * R_DSTS + t] * inv;
        }
        float2 hs = ((const float2*)hs2)[n];
        float o0 = g0 + hs.x;
        float o1 = g1 + hs.y;
        float mx = fmaxf(o0, o1), mn = fminf(o0, o1);
        float lse = mx + log1pf(__expf(mn - mx));
        ((float2*)out)[n] = make_float2(o0 - lse, o1 - lse);
    }
}

extern "C" void kernel_launch(void* const* d_in, const int* in_sizes, int n_in,
                              void* d_out, int out_size, void* d_ws, size_t ws_size,
                              hipStream_t stream) {
    const float* x   = (const float*)d_in[0];
    const int*   ei  = (const int*)d_in[1];
    const float* Wq1 = (const float*)d_in[2];
    const float* bq1 = (const float*)d_in[3];
    const float* Wk1 = (const float*)d_in[4];
    const float* bk1 = (const float*)d_in[5];
    const float* Wv1 = (const float*)d_in[6];
    const float* bv1 = (const float*)d_in[7];
    const float* Ws1 = (const float*)d_in[8];
    const float* bs1 = (const float*)d_in[9];
    const float* Wq2 = (const float*)d_in[10];
    const float* bq2 = (const float*)d_in[11];
    const float* Wk2 = (const float*)d_in[12];
    const float* bk2 = (const float*)d_in[13];
    const float* Wv2 = (const float*)d_in[14];
    const float* bv2 = (const float*)d_in[15];
    const float* Ws2 = (const float*)d_in[16];
    const float* bs2 = (const float*)d_in[17];

    const int N = in_sizes[0] / 2;
    const int E = in_sizes[1] / 2;
    const int* src = ei;
    const int* dst = ei + E;

    const int NB   = (N + R_DSTS - 1) >> R_LOG2;     // 1563
    const int NBlk = (E + BE - 1) / BE;              // 391

    // workspace layout (4-byte units); recs at a 16B-aligned offset
    float* ws = (float*)d_ws;
    size_t off = 0;
    int*   cnt  = (int*)(ws + off);      off += MAXNB;             // padded
    int*   recs = (int*)(ws + off);      off += (size_t)NB * CAPB; // %4==0
    off = (off + 3) & ~(size_t)3;        // 16B align
    float4* kv2 = (float4*)(ws + off);   off += 4 * (size_t)N;
    float* q2   = ws + off;              off += 2 * (size_t)N;
    float* hs2  = ws + off;              off += 2 * (size_t)N;

    hipMemsetAsync(cnt, 0, NB * sizeof(int), stream);
    scatter1_k<<<NBlk, 1024, 0, stream>>>(src, dst, cnt, recs, NB, E);
    l1proj_k<<<NB, 256, 0, stream>>>(x, Wq1, bq1, Wk1, bk1,
                                     Wv1, bv1, Ws1, bs1,
                                     Wq2, bq2, Wk2, bk2, Wv2, bv2, Ws2, bs2,
                                     recs, cnt, q2, kv2, hs2, N);
    l2out_k<<<NB, 256, 0, stream>>>(q2, kv2, hs2, recs, cnt, (float*)d_out, N);
}